// Round 7
// baseline (563.442 us; speedup 1.0000x reference)
//
#include <hip/hip_runtime.h>
#include <math.h>

#define N_NODES 20000
#define E_EDGES 320000
#define NHEADS 4
#define RMIN 2.2e-10f
#define THETA_MAX 1000.0f
#define SLOPE 0.2f
#define LOG2E 1.4426950408889634f
#define LOG2_LN2 -0.5287663729448977f  /* log2(ln 2) */

typedef unsigned short ushort_t;
typedef __attribute__((ext_vector_type(8))) short bf16x8;
typedef __attribute__((ext_vector_type(4))) float f32x4;

__device__ __forceinline__ float softplus_f(float x) {
    // log(1+exp(x)), stable; matches jax.nn.softplus (libm path: feeds outputs k,l,z)
    return fmaxf(x, 0.0f) + log1pf(expf(-fabsf(x)));
}

// exp(leaky_relu(s+d)) for one head — native v_exp_f32
__device__ __forceinline__ float ew1(float sv, float dh) {
    float e = (sv + dh) * LOG2E;
    e = e > 0.f ? e : SLOPE * e;
    return __builtin_amdgcn_exp2f(e);
}

// exact 3-way bf16 decomposition: a == a1 + a2 + a3 (24 mantissa bits via truncation)
__device__ __forceinline__ void split3(float a, ushort_t &h, ushort_t &m, ushort_t &l) {
    unsigned u = __float_as_uint(a);
    h = (ushort_t)(u >> 16);
    float r1 = a - __uint_as_float(u & 0xFFFF0000u);   // exact
    unsigned v = __float_as_uint(r1);
    m = (ushort_t)(v >> 16);
    float r2 = r1 - __uint_as_float(v & 0xFFFF0000u);  // exact
    l = (ushort_t)(__float_as_uint(r2) >> 16);         // exact (<=8 bits left)
}

// ---------------- CSR build ----------------
__global__ __launch_bounds__(256) void count_kernel(const int* __restrict__ dst,
                                                    int* __restrict__ deg) {
    int e = blockIdx.x * 256 + threadIdx.x;
    if (e < E_EDGES) atomicAdd(&deg[dst[e]], 1);
}

__global__ __launch_bounds__(256) void scan_kernel(const int* __restrict__ deg,
                                                   int* __restrict__ rowptr,
                                                   int* __restrict__ cursor) {
    __shared__ int part[256];
    int t = threadIdx.x;
    const int CH = (N_NODES + 255) / 256;  // 79
    int base = t * CH;
    int sum = 0;
    for (int i = 0; i < CH; ++i) {
        int idx = base + i;
        if (idx < N_NODES) sum += deg[idx];
    }
    part[t] = sum;
    __syncthreads();
    // Hillis-Steele inclusive scan
    for (int off = 1; off < 256; off <<= 1) {
        int v = (t >= off) ? part[t - off] : 0;
        __syncthreads();
        part[t] += v;
        __syncthreads();
    }
    int run = (t == 0) ? 0 : part[t - 1];
    for (int i = 0; i < CH; ++i) {
        int idx = base + i;
        if (idx < N_NODES) {
            rowptr[idx] = run;
            cursor[idx] = run;
            run += deg[idx];
        }
    }
    if (t == 255) rowptr[N_NODES] = run;
}

__global__ __launch_bounds__(256) void scatter_kernel(const int* __restrict__ src,
                                                      const int* __restrict__ dst,
                                                      int* __restrict__ cursor,
                                                      int* __restrict__ csr) {
    int e = blockIdx.x * 256 + threadIdx.x;
    if (e < E_EDGES) {
        int p = atomicAdd(&cursor[dst[e]], 1);
        csr[p] = src[e];
    }
}

// ---------------- MFMA GEMM: 64x64 tile, 4 waves, 3-way bf16 split (fp32-exact) ------
// out = A[M,K] * [W0;W1][NO,K]^T, K multiple of 32.
// Cols [0,split)->out0 (MODE0), [split,NO)->out1 (MODE1). MODE: 0 raw, 1 softplus(v+b).
// A/B fragment layout (16x16x32): lane holds 8 contiguous k at m/n = lane&15,
// k0 = (lane>>4)*8. C/D: col=lane&15, row=(lane>>4)*4+reg [HW-verified m89/m91].
__device__ __forceinline__ void stage3(float4 f0, float4 f1, ushort_t (*lds)[64][40],
                                       int row, int k8) {
    float f[8] = {f0.x, f0.y, f0.z, f0.w, f1.x, f1.y, f1.z, f1.w};
    bf16x8 v1, v2, v3;
#pragma unroll
    for (int j = 0; j < 8; ++j) {
        ushort_t h, m, l;
        split3(f[j], h, m, l);
        v1[j] = (short)h; v2[j] = (short)m; v3[j] = (short)l;
    }
    *(bf16x8*)&lds[0][row][k8] = v1;
    *(bf16x8*)&lds[1][row][k8] = v2;
    *(bf16x8*)&lds[2][row][k8] = v3;
}

template <int MODE>
__device__ __forceinline__ void epilogueM(const f32x4 acc[2][2], const float* __restrict__ bp,
                                          float* __restrict__ op, int ow, int colbase,
                                          int bm, int wr, int wc, int lane, int M) {
#pragma unroll
    for (int rt = 0; rt < 2; ++rt) {
#pragma unroll
        for (int ct = 0; ct < 2; ++ct) {
            int col = colbase + wc * 32 + ct * 16 + (lane & 15);
            float bv = (MODE != 0) ? bp[col] : 0.f;
#pragma unroll
            for (int r = 0; r < 4; ++r) {
                int m = bm + wr * 32 + rt * 16 + (lane >> 4) * 4 + r;
                if (m < M) {
                    float v = acc[rt][ct][r];
                    if (MODE == 1) v = softplus_f(v + bv);
                    op[(size_t)m * ow + col] = v;
                }
            }
        }
    }
}

template <int MODE0, int MODE1>
__global__ __launch_bounds__(256) void gemmM_kernel(const float* __restrict__ A,
                                                    const float* __restrict__ W0,
                                                    const float* __restrict__ W1,
                                                    const float* __restrict__ b0p,
                                                    const float* __restrict__ b1p,
                                                    float* __restrict__ out0,
                                                    float* __restrict__ out1,
                                                    int M, int K, int split,
                                                    int ow0, int ow1) {
    __shared__ ushort_t Alds[3][64][40];  // 3 split-levels, 64 rows, 32 k (+8 pad)
    __shared__ ushort_t Blds[3][64][40];
    int tid = threadIdx.x;
    int lane = tid & 63, w = tid >> 6, wr = w >> 1, wc = w & 1;
    int bm = blockIdx.x * 64, bn = blockIdx.y * 64;
    bool first = bn < split;
    const float* Wb = first ? (W0 + (size_t)bn * K) : (W1 + (size_t)(bn - split) * K);
    int srow = tid >> 2;          // 0..63
    int sk8 = (tid & 3) * 8;      // 0,8,16,24
    int arow_g = bm + srow;
    bool avalid = arow_g < M;
    const float* Ap = A + (size_t)arow_g * K + sk8;
    const float* Wp = Wb + (size_t)srow * K + sk8;

    // prefetch chunk 0 (32 B per operand per thread)
    float4 a0 = make_float4(0.f, 0.f, 0.f, 0.f), a1 = a0;
    if (avalid) { a0 = *(const float4*)(Ap); a1 = *(const float4*)(Ap + 4); }
    float4 b0 = *(const float4*)(Wp), b1 = *(const float4*)(Wp + 4);

    f32x4 acc[2][2];
#pragma unroll
    for (int i = 0; i < 2; ++i)
#pragma unroll
        for (int j = 0; j < 2; ++j) acc[i][j] = (f32x4){0.f, 0.f, 0.f, 0.f};

    int T = K >> 5;
    for (int t = 0; t < T; ++t) {
        stage3(a0, a1, Alds, srow, sk8);
        stage3(b0, b1, Blds, srow, sk8);
        __syncthreads();
        if (t + 1 < T) {
            int ko = (t + 1) << 5;
            if (avalid) { a0 = *(const float4*)(Ap + ko); a1 = *(const float4*)(Ap + ko + 4); }
            b0 = *(const float4*)(Wp + ko); b1 = *(const float4*)(Wp + ko + 4);
        }
        int koff = (lane >> 4) * 8;
#pragma unroll
        for (int rt = 0; rt < 2; ++rt) {
            int ar = wr * 32 + rt * 16 + (lane & 15);
            bf16x8 A1 = *(const bf16x8*)&Alds[0][ar][koff];
            bf16x8 A2 = *(const bf16x8*)&Alds[1][ar][koff];
            bf16x8 A3 = *(const bf16x8*)&Alds[2][ar][koff];
#pragma unroll
            for (int ct = 0; ct < 2; ++ct) {
                int br = wc * 32 + ct * 16 + (lane & 15);
                bf16x8 B1 = *(const bf16x8*)&Blds[0][br][koff];
                bf16x8 B2 = *(const bf16x8*)&Blds[1][br][koff];
                bf16x8 B3 = *(const bf16x8*)&Blds[2][br][koff];
                f32x4 c = acc[rt][ct];
                // small terms first for accumulation accuracy
                c = __builtin_amdgcn_mfma_f32_16x16x32_bf16(A1, B3, c, 0, 0, 0);
                c = __builtin_amdgcn_mfma_f32_16x16x32_bf16(A3, B1, c, 0, 0, 0);
                c = __builtin_amdgcn_mfma_f32_16x16x32_bf16(A2, B2, c, 0, 0, 0);
                c = __builtin_amdgcn_mfma_f32_16x16x32_bf16(A1, B2, c, 0, 0, 0);
                c = __builtin_amdgcn_mfma_f32_16x16x32_bf16(A2, B1, c, 0, 0, 0);
                c = __builtin_amdgcn_mfma_f32_16x16x32_bf16(A1, B1, c, 0, 0, 0);
                acc[rt][ct] = c;
            }
        }
        __syncthreads();
    }
    if (first) epilogueM<MODE0>(acc, b0p, out0, ow0, bn, bm, wr, wc, lane, M);
    else       epilogueM<MODE1>(acc, b1p, out1, ow1, bn - split, bm, wr, wc, lane, M);
}

// ---------------- per-node attention logits s,d (standalone) ----------------
template <int F, int CPER>
__global__ __launch_bounds__(256) void sd_kernel(const float* __restrict__ xw,
                                                 const float* __restrict__ asrc,
                                                 const float* __restrict__ adst,
                                                 float* __restrict__ s,
                                                 float* __restrict__ d) {
    int wave = threadIdx.x >> 6;
    int lane = threadIdx.x & 63;
    int n = blockIdx.x * 4 + wave;
    if (n >= N_NODES) return;
    float ss[NHEADS] = {0, 0, 0, 0}, dd[NHEADS] = {0, 0, 0, 0};
#pragma unroll
    for (int j = 0; j < F / 64; ++j) {
        int c = j * 64 + lane;
        int h = c / CPER;
        int cc = c % CPER;
        float v = xw[(size_t)n * F + c];
        ss[h] += v * asrc[h * CPER + cc];
        dd[h] += v * adst[h * CPER + cc];
    }
#pragma unroll
    for (int off = 32; off > 0; off >>= 1) {
#pragma unroll
        for (int h = 0; h < NHEADS; ++h) {
            ss[h] += __shfl_xor(ss[h], off, 64);
            dd[h] += __shfl_xor(dd[h], off, 64);
        }
    }
    if (lane == 0) {
#pragma unroll
        for (int h = 0; h < NHEADS; ++h) {
            s[n * NHEADS + h] = ss[h];
            d[n * NHEADS + h] = dd[h];
        }
    }
}

// ---------------- vector GEMM (kept for small tail GEMMs) ----------------
template <int MODE, bool TRANS>
__device__ __forceinline__ void gemm_epilogue4(const float acc[4][4],
                                               const float* __restrict__ bp,
                                               float* __restrict__ op,
                                               int ow, int colbase, int r0, int lc, int M) {
    float bv[4] = {0.f, 0.f, 0.f, 0.f};
    if (MODE != 0) *(float4*)bv = *(const float4*)(bp + colbase + lc);
    float vals[4][4];
#pragma unroll
    for (int i = 0; i < 4; ++i)
#pragma unroll
        for (int j = 0; j < 4; ++j) {
            float v = acc[i][j];
            if (MODE == 1) v = softplus_f(v + bv[j]);
            else if (MODE == 2) { v = softplus_f(v + bv[j]); v = fminf(fmaxf(v, 0.1f), 1000.0f); }
            else if (MODE == 3) { v = fmaxf(softplus_f(v + bv[j]), RMIN); }
            vals[i][j] = v;
        }
    if (!TRANS) {
#pragma unroll
        for (int i = 0; i < 4; ++i) {
            int row = r0 + i;
            if (row < M) *(float4*)(op + (size_t)row * ow + colbase + lc) = *(float4*)vals[i];
        }
    } else {
        if (r0 + 3 < M) {
#pragma unroll
            for (int j = 0; j < 4; ++j) {
                int c = colbase + lc + j;
                float col[4] = {vals[0][j], vals[1][j], vals[2][j], vals[3][j]};
                *(float4*)(op + (size_t)c * M + r0) = *(float4*)col;
            }
        } else {
#pragma unroll
            for (int i = 0; i < 4; ++i) {
                int row = r0 + i;
                if (row < M)
#pragma unroll
                    for (int j = 0; j < 4; ++j) op[(size_t)(colbase + lc + j) * M + row] = vals[i][j];
            }
        }
    }
}

template <int MODE0, int MODE1, bool TRANS>
__global__ __launch_bounds__(256) void gemm64_kernel(const float* __restrict__ A,
                                                     const float* __restrict__ W0,
                                                     const float* __restrict__ W1,
                                                     const float* __restrict__ b0p,
                                                     const float* __restrict__ b1p,
                                                     float* __restrict__ out0,
                                                     float* __restrict__ out1,
                                                     int M, int K, int split, int no1) {
    __shared__ float As[16][68];
    __shared__ float Bs[16][68];
    int tid = threadIdx.x;
    int tx = tid & 15, ty = tid >> 4;
    int bm = blockIdx.x * 64;
    int bn = blockIdx.y * 64;
    bool first = bn < split;
    const float* W = first ? (W0 + (size_t)bn * K) : (W1 + (size_t)(bn - split) * K);
    int m = tid >> 2;
    int kk0 = (tid & 3) * 4;
    int arow = bm + m;
    bool avalid = arow < M;
    const float* Ap = A + (size_t)arow * K + kk0;
    const float* Wp = W + (size_t)m * K + kk0;

    float4 av = make_float4(0.f, 0.f, 0.f, 0.f);
    if (avalid) av = *(const float4*)(Ap);
    float4 bv = *(const float4*)(Wp);

    float acc[4][4] = {};
    int T = K >> 4;
    for (int t = 0; t < T; ++t) {
        As[kk0 + 0][m] = av.x; As[kk0 + 1][m] = av.y;
        As[kk0 + 2][m] = av.z; As[kk0 + 3][m] = av.w;
        Bs[kk0 + 0][m] = bv.x; Bs[kk0 + 1][m] = bv.y;
        Bs[kk0 + 2][m] = bv.z; Bs[kk0 + 3][m] = bv.w;
        __syncthreads();
        if (t + 1 < T) {
            int ko = (t + 1) << 4;
            if (avalid) av = *(const float4*)(Ap + ko);
            bv = *(const float4*)(Wp + ko);
        }
#pragma unroll
        for (int kk = 0; kk < 16; ++kk) {
            float a[4], b[4];
            *(float4*)a = *(const float4*)(&As[kk][ty * 4]);
            *(float4*)b = *(const float4*)(&Bs[kk][tx * 4]);
#pragma unroll
            for (int i = 0; i < 4; ++i)
#pragma unroll
                for (int j = 0; j < 4; ++j) acc[i][j] += a[i] * b[j];
        }
        __syncthreads();
    }
    int r0 = bm + ty * 4;
    int lc = tx * 4;
    if (first) gemm_epilogue4<MODE0, TRANS>(acc, b0p, out0, split, bn, r0, lc, M);
    else       gemm_epilogue4<MODE1, TRANS>(acc, b1p, out1, no1, bn - split, r0, lc, M);
}

// ---------------- merged tail GEMM: y=0 -> z1 = sp(h1@fcW1^T+b); y=1..4 -> k0/l0 heads ----
__global__ __launch_bounds__(256) void gemmC_kernel(const float* __restrict__ h1,
                                                    const float* __restrict__ fcW1,
                                                    const float* __restrict__ fcb1,
                                                    float* __restrict__ z1,
                                                    const float* __restrict__ z0,
                                                    const float* __restrict__ shW0,
                                                    const float* __restrict__ shb0,
                                                    float* __restrict__ k0,
                                                    const float* __restrict__ scW0,
                                                    const float* __restrict__ scb0,
                                                    float* __restrict__ l0,
                                                    int M) {
    constexpr int K = 128;
    __shared__ float As[16][68];
    __shared__ float Bs[16][68];
    int tid = threadIdx.x;
    int tx = tid & 15, ty = tid >> 4;
    int bm = blockIdx.x * 64;
    int y = blockIdx.y;
    const float* A;
    const float* W;
    if (y == 0)      { A = h1; W = fcW1; }
    else if (y <= 2) { A = z0; W = shW0 + (size_t)(y - 1) * 64 * K; }
    else             { A = z0; W = scW0 + (size_t)(y - 3) * 64 * K; }
    int m = tid >> 2;
    int kk0 = (tid & 3) * 4;
    int arow = bm + m;
    bool avalid = arow < M;
    const float* Ap = A + (size_t)arow * K + kk0;
    const float* Wp = W + (size_t)m * K + kk0;

    float4 av = make_float4(0.f, 0.f, 0.f, 0.f);
    if (avalid) av = *(const float4*)(Ap);
    float4 bv = *(const float4*)(Wp);

    float acc[4][4] = {};
    constexpr int T = K >> 4;
    for (int t = 0; t < T; ++t) {
        As[kk0 + 0][m] = av.x; As[kk0 + 1][m] = av.y;
        As[kk0 + 2][m] = av.z; As[kk0 + 3][m] = av.w;
        Bs[kk0 + 0][m] = bv.x; Bs[kk0 + 1][m] = bv.y;
        Bs[kk0 + 2][m] = bv.z; Bs[kk0 + 3][m] = bv.w;
        __syncthreads();
        if (t + 1 < T) {
            int ko = (t + 1) << 4;
            if (avalid) av = *(const float4*)(Ap + ko);
            bv = *(const float4*)(Wp + ko);
        }
#pragma unroll
        for (int kk = 0; kk < 16; ++kk) {
            float a[4], b[4];
            *(float4*)a = *(const float4*)(&As[kk][ty * 4]);
            *(float4*)b = *(const float4*)(&Bs[kk][tx * 4]);
#pragma unroll
            for (int i = 0; i < 4; ++i)
#pragma unroll
                for (int j = 0; j < 4; ++j) acc[i][j] += a[i] * b[j];
        }
        __syncthreads();
    }
    int r0 = bm + ty * 4;
    int lc = tx * 4;
    if (y == 0)      gemm_epilogue4<1, false>(acc, fcb1, z1, 64, 0, r0, lc, M);
    else if (y <= 2) gemm_epilogue4<2, true>(acc, shb0, k0, 128, (y - 1) * 64, r0, lc, M);
    else             gemm_epilogue4<3, true>(acc, scb0, l0, 128, (y - 3) * 64, r0, lc, M);
}

// ---------------- GAT aggregation: one wave per node, per-lane VEC-column blocking ----
template <int F>
__global__ __launch_bounds__(256) void agg_kernel(const float* __restrict__ xw,
                                                  const int* __restrict__ rowptr,
                                                  const int* __restrict__ csr,
                                                  const float* __restrict__ s,
                                                  const float* __restrict__ d,
                                                  const float* __restrict__ bias,
                                                  float* __restrict__ out) {
    constexpr int VEC = F / 64;
    int wave = threadIdx.x >> 6;
    int lane = threadIdx.x & 63;
    int n = blockIdx.x * 4 + wave;
    if (n >= N_NODES) return;
    int c0 = lane * VEC;
    int h = lane >> 4;

    float dh = d[(size_t)n * NHEADS + h];
    float w = ew1(s[(size_t)n * NHEADS + h], dh);  // self-loop weight (own head)
    float den = w;
    float acc[VEC];
    {
        float r[VEC];
        const float* rp = xw + (size_t)n * F + c0;
        if constexpr (VEC == 4) *(float4*)r = *(const float4*)rp;
        else                    *(float2*)r = *(const float2*)rp;
#pragma unroll
        for (int v = 0; v < VEC; ++v) acc[v] = w * r[v];
    }

    int idx = rowptr[n], end = rowptr[n + 1];
    for (; idx + 4 <= end; idx += 4) {
        int n0 = csr[idx], n1 = csr[idx + 1], n2 = csr[idx + 2], n3 = csr[idx + 3];
        float w0 = ew1(s[(size_t)n0 * NHEADS + h], dh);
        float w1 = ew1(s[(size_t)n1 * NHEADS + h], dh);
        float w2 = ew1(s[(size_t)n2 * NHEADS + h], dh);
        float w3 = ew1(s[(size_t)n3 * NHEADS + h], dh);
        den += w0; den += w1; den += w2; den += w3;
        float r0[VEC], r1[VEC], r2[VEC], r3[VEC];
        const float* p0 = xw + (size_t)n0 * F + c0;
        const float* p1 = xw + (size_t)n1 * F + c0;
        const float* p2 = xw + (size_t)n2 * F + c0;
        const float* p3 = xw + (size_t)n3 * F + c0;
        if constexpr (VEC == 4) {
            *(float4*)r0 = *(const float4*)p0; *(float4*)r1 = *(const float4*)p1;
            *(float4*)r2 = *(const float4*)p2; *(float4*)r3 = *(const float4*)p3;
        } else {
            *(float2*)r0 = *(const float2*)p0; *(float2*)r1 = *(const float2*)p1;
            *(float2*)r2 = *(const float2*)p2; *(float2*)r3 = *(const float2*)p3;
        }
#pragma unroll
        for (int v = 0; v < VEC; ++v) {
            acc[v] += w0 * r0[v];
            acc[v] += w1 * r1[v];
            acc[v] += w2 * r2[v];
            acc[v] += w3 * r3[v];
        }
    }
    for (; idx < end; ++idx) {
        int n0 = csr[idx];
        float w0 = ew1(s[(size_t)n0 * NHEADS + h], dh);
        den += w0;
        float r0[VEC];
        const float* p0 = xw + (size_t)n0 * F + c0;
        if constexpr (VEC == 4) *(float4*)r0 = *(const float4*)p0;
        else                    *(float2*)r0 = *(const float2*)p0;
#pragma unroll
        for (int v = 0; v < VEC; ++v) acc[v] += w0 * r0[v];
    }

    float rden = 1.0f / (den + 1e-16f);
    float o[VEC], bvv[VEC];
    const float* bp = bias + c0;
    if constexpr (VEC == 4) *(float4*)bvv = *(const float4*)bp;
    else                    *(float2*)bvv = *(const float2*)bp;
#pragma unroll
    for (int v = 0; v < VEC; ++v) o[v] = acc[v] * rden + bvv[v];
    float* op = out + (size_t)n * F + c0;
    if constexpr (VEC == 4) *(float4*)op = *(float4*)o;
    else                    *(float2*)op = *(float2*)o;
}

// ---------------- Weibull reparameterization: native v_log/v_exp power chain ----------------
__device__ __forceinline__ void theta_work(const float* __restrict__ eps,
                                           const float* __restrict__ kptr,
                                           float* __restrict__ lptr,
                                           float* __restrict__ theta, int i, int ZN) {
    float k = kptr[i];
    float invk = __builtin_amdgcn_rcpf(k);          // k in [0.1,1000], ~1ulp
    float lg = lgammaf(1.0f + invk);                // keep libm: 1 call, accuracy-critical
    float l = lptr[i] * __builtin_amdgcn_exp2f(-lg * LOG2E);  // l / Gamma(1+invk)
    lptr[i] = l;
    float c = invk * LOG2_LN2;
    float acc = 0.0f;
#pragma unroll
    for (int ss = 0; ss < 10; ++ss) {
        float u = eps[(size_t)ss * ZN + i];
        float t = -__builtin_amdgcn_logf(fmaxf(1.0f - u, RMIN));   // -log2(1-u) >= 0
        acc += __builtin_amdgcn_exp2f(invk * __builtin_amdgcn_logf(t) + c);
    }
    float th = l * acc * 0.1f;
    th = fminf(fmaxf(th, RMIN), THETA_MAX);
    theta[i] = th;
}

__global__ __launch_bounds__(256) void theta2_kernel(const float* __restrict__ eps0,
                                                     float* __restrict__ k0,
                                                     float* __restrict__ l0,
                                                     float* __restrict__ th0,
                                                     const float* __restrict__ eps1,
                                                     float* __restrict__ k1,
                                                     float* __restrict__ l1,
                                                     float* __restrict__ th1) {
    int i = blockIdx.x * 256 + threadIdx.x;
    if (i < 2560000) {
        theta_work(eps0, k0, l0, th0, i, 2560000);
    } else {
        int j = i - 2560000;
        if (j < 1280000) theta_work(eps1, k1, l1, th1, j, 1280000);
    }
}

extern "C" void kernel_launch(void* const* d_in, const int* in_sizes, int n_in,
                              void* d_out, int out_size, void* d_ws, size_t ws_size,
                              hipStream_t stream) {
    const float* x     = (const float*)d_in[0];
    const int*   eidx  = (const int*)d_in[1];
    const float* gatW0 = (const float*)d_in[2];
    const float* asrc0 = (const float*)d_in[3];
    const float* adst0 = (const float*)d_in[4];
    const float* gatb0 = (const float*)d_in[5];
    const float* fcW0  = (const float*)d_in[6];
    const float* fcb0  = (const float*)d_in[7];
    const float* shW0  = (const float*)d_in[8];
    const float* shb0  = (const float*)d_in[9];
    const float* scW0  = (const float*)d_in[10];
    const float* scb0  = (const float*)d_in[11];
    const float* gatW1 = (const float*)d_in[12];
    const float* asrc1 = (const float*)d_in[13];
    const float* adst1 = (const float*)d_in[14];
    const float* gatb1 = (const float*)d_in[15];
    const float* fcW1  = (const float*)d_in[16];
    const float* fcb1  = (const float*)d_in[17];
    const float* shW1  = (const float*)d_in[18];
    const float* shb1  = (const float*)d_in[19];
    const float* scW1  = (const float*)d_in[20];
    const float* scb1  = (const float*)d_in[21];
    const float* eps0  = (const float*)d_in[22];
    const float* eps1  = (const float*)d_in[23];

    const int* e_src = eidx;
    const int* e_dst = eidx + E_EDGES;

    // workspace carve-up
    size_t off = 0;
    auto carve = [&](size_t elems) {
        void* p = (char*)d_ws + off;
        off += ((elems * 4 + 255) / 256) * 256;
        return p;
    };
    float* xw0 = (float*)carve(20000u * 256);
    float* h0  = (float*)carve(20000u * 256);
    float* z0  = (float*)carve(20000u * 128);
    float* xw1 = (float*)carve(20000u * 128);
    float* h1  = (float*)carve(20000u * 128);
    float* z1  = (float*)carve(20000u * 64);
    float* s0  = (float*)carve(20000u * 4);
    float* d0  = (float*)carve(20000u * 4);
    float* s1  = (float*)carve(20000u * 4);
    float* d1  = (float*)carve(20000u * 4);
    int* deg    = (int*)carve(20000);
    int* rowptr = (int*)carve(20001);
    int* cursor = (int*)carve(20000);
    int* csr    = (int*)carve(E_EDGES);

    float* out    = (float*)d_out;
    float* theta0 = out;
    float* theta1 = out + 2560000;
    float* k0     = out + 3840000;
    float* k1     = out + 6400000;
    float* l0     = out + 7680000;
    float* l1     = out + 10240000;

    const int M = N_NODES;
    dim3 blk(256);
    const int GX = (N_NODES + 63) / 64;  // 313

    // CSR build
    (void)hipMemsetAsync(deg, 0, N_NODES * sizeof(int), stream);
    count_kernel<<<(E_EDGES + 255) / 256, blk, 0, stream>>>(e_dst, deg);
    scan_kernel<<<1, blk, 0, stream>>>(deg, rowptr, cursor);
    scatter_kernel<<<(E_EDGES + 255) / 256, blk, 0, stream>>>(e_src, e_dst, cursor, csr);

    // layer 0: xw0 = x @ gatW0^T  (MFMA, fp32-exact 3-way bf16 split)
    gemmM_kernel<0, 0><<<dim3(GX, 4), blk, 0, stream>>>(
        x, gatW0, nullptr, nullptr, nullptr, xw0, nullptr, M, 256, 256, 256, 0);
    sd_kernel<256, 64><<<5000, blk, 0, stream>>>(xw0, asrc0, adst0, s0, d0);
    agg_kernel<256><<<5000, blk, 0, stream>>>(xw0, rowptr, csr, s0, d0, gatb0, h0);

    // merged: z0 = softplus(h0 @ fcW0^T + b) | xw1 = h0 @ gatW1^T  (MFMA)
    gemmM_kernel<1, 0><<<dim3(GX, 4), blk, 0, stream>>>(
        h0, fcW0, gatW1, fcb0, nullptr, z0, xw1, M, 256, 128, 128, 128);
    sd_kernel<128, 32><<<5000, blk, 0, stream>>>(xw1, asrc1, adst1, s1, d1);
    agg_kernel<128><<<5000, blk, 0, stream>>>(xw1, rowptr, csr, s1, d1, gatb1, h1);

    // merged tail: z1 gemm + z0-heads gemms (K=128 for all five y-tiles)
    gemmC_kernel<<<dim3(GX, 5), blk, 0, stream>>>(
        h1, fcW1, fcb1, z1, z0, shW0, shb0, k0, scW0, scb0, l0, M);

    // z1 heads (K=64): k1 = clip(sp(.)), l1 = max(sp(.), RMIN), transposed
    gemm64_kernel<2, 3, true><<<dim3(GX, 2), blk, 0, stream>>>(
        z1, shW1, scW1, shb1, scb1, k1, l1, M, 64, 64, 64);

    // reparameterize both levels (finalizes l in-place, writes theta)
    theta2_kernel<<<15000, blk, 0, stream>>>(eps0, k0, l0, theta0, eps1, k1, l1, theta1);
}